// Round 1
// baseline (94.431 us; speedup 1.0000x reference)
//
#include <hip/hip_runtime.h>

#define B_ROWS 32768
#define NPROTO 2048
#define NOUT   200
#define LAT    40

// ws layout (floats):
//  [0..39]      proto_sum
//  [40]         proto_sq
//  [64..263]    wsum[200]
//  [512..33279] d[32768]
//  [33280..33791] partial min (512)
//  [33792..34303] partial sum (512)

__global__ void pc_setup(const float* __restrict__ protos,
                         const float* __restrict__ w,
                         float* __restrict__ ws) {
    const int b = blockIdx.x;
    const int t = threadIdx.x;
    if (b < NOUT) {
        // wsum[b] = sum_p w[b, p]
        float acc = 0.f;
        const float* row = w + b * NPROTO;
        for (int k = t; k < NPROTO; k += 256) acc += row[k];
        __shared__ float sred[4];
        #pragma unroll
        for (int off = 32; off > 0; off >>= 1) acc += __shfl_down(acc, off, 64);
        if ((t & 63) == 0) sred[t >> 6] = acc;
        __syncthreads();
        if (t == 0) ws[64 + b] = sred[0] + sred[1] + sred[2] + sred[3];
    } else {
        // proto_sum (per-dim) + proto_sq (scalar)
        __shared__ float sdim[6][40];
        __shared__ float ssq[4];
        float sq = 0.f;
        if (t < 240) {
            const int d = t % 40, g = t / 40;
            float acc = 0.f;
            for (int p = g; p < NPROTO; p += 6) {
                float v = protos[p * LAT + d];
                acc += v;
                sq += v * v;
            }
            sdim[g][d] = acc;
        }
        #pragma unroll
        for (int off = 32; off > 0; off >>= 1) sq += __shfl_down(sq, off, 64);
        if ((t & 63) == 0) ssq[t >> 6] = sq;
        __syncthreads();
        if (t < 40) {
            float s = 0.f;
            #pragma unroll
            for (int g = 0; g < 6; ++g) s += sdim[g][t];
            ws[t] = s;
        }
        if (t == 0) ws[40] = ssq[0] + ssq[1] + ssq[2] + ssq[3];
    }
}

__global__ __launch_bounds__(64) void pc_dist(const float* __restrict__ x,
                                              float* __restrict__ ws) {
    __shared__ float sps[40];
    const int t = threadIdx.x;
    if (t < 40) sps[t] = ws[t];
    __syncthreads();
    const float psq = ws[40];
    const int row = blockIdx.x * 64 + t;
    const float4* xr = (const float4*)(x + row * LAT);
    float ssq = 0.f, dot = 0.f;
    #pragma unroll
    for (int k = 0; k < 10; ++k) {
        float4 v = xr[k];
        ssq += v.x * v.x + v.y * v.y + v.z * v.z + v.w * v.w;
        dot += v.x * sps[4 * k] + v.y * sps[4 * k + 1] +
               v.z * sps[4 * k + 2] + v.w * sps[4 * k + 3];
    }
    const float s = 2048.f * ssq - 2.f * dot + psq;
    const float d = sqrtf(s);
    ws[512 + row] = d;
    float mn = d, sm = d;
    #pragma unroll
    for (int off = 32; off > 0; off >>= 1) {
        mn = fminf(mn, __shfl_down(mn, off, 64));
        sm += __shfl_down(sm, off, 64);
    }
    if (t == 0) {
        ws[33280 + blockIdx.x] = mn;
        ws[33792 + blockIdx.x] = sm;
    }
}

__global__ void pc_out(const float* __restrict__ bias,
                       const float* __restrict__ ws,
                       float* __restrict__ out) {
    const float*  dvec = ws + 512;
    const float2* w2   = (const float2*)(ws + 64);
    const float2* b2   = (const float2*)bias;
    float2*       o    = (float2*)(out + 2);
    const unsigned T = (unsigned)(B_ROWS * NOUT) / 2u;  // 3,276,800 float2 pairs
    const unsigned stride = gridDim.x * blockDim.x;
    for (unsigned idx = blockIdx.x * blockDim.x + threadIdx.x; idx < T; idx += stride) {
        const unsigned i = idx / 100u;          // row
        const unsigned j = idx - i * 100u;      // column pair
        const float  d  = dvec[i];
        const float2 wv = w2[j];
        const float2 bv = b2[j];
        float2 r;
        r.x = d * wv.x + bv.x;
        r.y = d * wv.y + bv.y;
        o[idx] = r;  // out pair index == i*100 + j == idx
    }
}

__global__ void pc_finish(const float* __restrict__ ws, float* __restrict__ out) {
    const int t = threadIdx.x;  // 256 threads, 512 partials each
    float mn = fminf(ws[33280 + t], ws[33280 + 256 + t]);
    float sm = ws[33792 + t] + ws[33792 + 256 + t];
    __shared__ float smn[4], ssm[4];
    #pragma unroll
    for (int off = 32; off > 0; off >>= 1) {
        mn = fminf(mn, __shfl_down(mn, off, 64));
        sm += __shfl_down(sm, off, 64);
    }
    if ((t & 63) == 0) { smn[t >> 6] = mn; ssm[t >> 6] = sm; }
    __syncthreads();
    if (t == 0) {
        out[0] = fminf(fminf(smn[0], smn[1]), fminf(smn[2], smn[3]));
        out[1] = (ssm[0] + ssm[1] + ssm[2] + ssm[3]) * (1.0f / 32768.0f);
    }
}

extern "C" void kernel_launch(void* const* d_in, const int* in_sizes, int n_in,
                              void* d_out, int out_size, void* d_ws, size_t ws_size,
                              hipStream_t stream) {
    const float* x      = (const float*)d_in[0];
    const float* protos = (const float*)d_in[1];
    const float* w      = (const float*)d_in[2];
    const float* bias   = (const float*)d_in[3];
    float* out = (float*)d_out;
    float* ws  = (float*)d_ws;

    pc_setup<<<201, 256, 0, stream>>>(protos, w, ws);
    pc_dist<<<512, 64, 0, stream>>>(x, ws);
    pc_out<<<2048, 256, 0, stream>>>(bias, ws, out);
    pc_finish<<<1, 256, 0, stream>>>(ws, out);
}

// Round 2
// 23.872 us; speedup vs baseline: 3.9557x; 3.9557x over previous
//
#include <hip/hip_runtime.h>

#define B_ROWS 32768
#define NPROTO 2048
#define NOUT   200
#define LAT    40
#define PBLK   16      // proto-reduction blocks
#define DBLK   256     // pc_dist blocks (x128 threads)

// ws layout (floats), max index 34303 (= 137,216 bytes, same as r1):
//  [0..199]      wsum[200]
//  [200..215]    proto_sq partials (16)
//  [256..895]    proto_sum partials [16][40]
//  [896..1151]   block min partials (256)
//  [1152..1407]  block sum partials (256)
//  [1536..34303] d[32768]

__global__ __launch_bounds__(320) void pc_stage1(const float* __restrict__ protos,
                                                 const float* __restrict__ w,
                                                 float* __restrict__ ws) {
    const int b = blockIdx.x;
    const int t = threadIdx.x;
    __shared__ float sred[5];
    __shared__ float sdim[8][40];
    __shared__ float ssq[5];
    if (b < NOUT) {
        // wsum[b] = sum_p w[b, p] — coalesced, 7 iters
        float acc = 0.f;
        const float* row = w + b * NPROTO;
        for (int k = t; k < NPROTO; k += 320) acc += row[k];
        #pragma unroll
        for (int off = 32; off > 0; off >>= 1) acc += __shfl_down(acc, off, 64);
        if ((t & 63) == 0) sred[t >> 6] = acc;
        __syncthreads();
        if (t == 0) ws[b] = sred[0] + sred[1] + sred[2] + sred[3] + sred[4];
    } else {
        // proto partial reduction: 16 blocks x 320 threads, d = t%40 invariant
        const int rel = b - NOUT;          // 0..15
        const int d = t % 40, g = t / 40;  // 8 groups of 40
        float sum = 0.f, sq = 0.f;
        for (int idx = rel * 320 + t; idx < NPROTO * LAT; idx += PBLK * 320) {
            float v = protos[idx];          // coalesced; idx%40 == d always
            sum += v;
            sq  += v * v;
        }
        sdim[g][d] = sum;
        #pragma unroll
        for (int off = 32; off > 0; off >>= 1) sq += __shfl_down(sq, off, 64);
        if ((t & 63) == 0) ssq[t >> 6] = sq;
        __syncthreads();
        if (t < 40) {
            float s = 0.f;
            #pragma unroll
            for (int g2 = 0; g2 < 8; ++g2) s += sdim[g2][t];
            ws[256 + rel * 40 + t] = s;
        }
        if (t == 0) ws[200 + rel] = ssq[0] + ssq[1] + ssq[2] + ssq[3] + ssq[4];
    }
}

__global__ __launch_bounds__(128) void pc_dist(const float* __restrict__ x,
                                               float* __restrict__ ws) {
    __shared__ float sps[40];
    __shared__ float spsq;
    __shared__ float redmn[2], redsm[2];
    const int t = threadIdx.x;
    // fold proto partials (L2-hot)
    if (t < 40) {
        float s = 0.f;
        #pragma unroll
        for (int j = 0; j < PBLK; ++j) s += ws[256 + j * 40 + t];
        sps[t] = s;
    }
    if (t == 64) {
        float s = 0.f;
        #pragma unroll
        for (int j = 0; j < PBLK; ++j) s += ws[200 + j];
        spsq = s;
    }
    __syncthreads();
    const float psq = spsq;
    const int row = blockIdx.x * 128 + t;
    const float4* xr = (const float4*)(x + row * LAT);
    float ssq = 0.f, dot = 0.f;
    #pragma unroll
    for (int k = 0; k < 10; ++k) {
        float4 v = xr[k];
        ssq += v.x * v.x + v.y * v.y + v.z * v.z + v.w * v.w;
        dot += v.x * sps[4 * k] + v.y * sps[4 * k + 1] +
               v.z * sps[4 * k + 2] + v.w * sps[4 * k + 3];
    }
    const float s = 2048.f * ssq - 2.f * dot + psq;
    const float d = sqrtf(s);
    ws[1536 + row] = d;
    float mn = d, sm = d;
    #pragma unroll
    for (int off = 32; off > 0; off >>= 1) {
        mn = fminf(mn, __shfl_down(mn, off, 64));
        sm += __shfl_down(sm, off, 64);
    }
    if ((t & 63) == 0) { redmn[t >> 6] = mn; redsm[t >> 6] = sm; }
    __syncthreads();
    if (t == 0) {
        ws[896 + blockIdx.x]  = fminf(redmn[0], redmn[1]);
        ws[1152 + blockIdx.x] = redsm[0] + redsm[1];
    }
}

__global__ void pc_out(const float* __restrict__ bias,
                       const float* __restrict__ ws,
                       float* __restrict__ out) {
    const float*  dvec = ws + 1536;
    const float2* w2   = (const float2*)ws;        // wsum at ws[0..199]
    const float2* b2   = (const float2*)bias;
    float2*       o    = (float2*)(out + 2);       // out+2 is 8B-aligned
    const unsigned T = (unsigned)(B_ROWS * NOUT) / 2u;  // 3,276,800 pairs
    const unsigned stride = gridDim.x * blockDim.x;
    for (unsigned idx = blockIdx.x * blockDim.x + threadIdx.x; idx < T; idx += stride) {
        const unsigned i = idx / 100u;          // row
        const unsigned j = idx - i * 100u;      // column pair
        const float  d  = dvec[i];
        const float2 wv = w2[j];
        const float2 bv = b2[j];
        float2 r;
        r.x = d * wv.x + bv.x;
        r.y = d * wv.y + bv.y;
        o[idx] = r;
    }
}

__global__ void pc_finish(const float* __restrict__ ws, float* __restrict__ out) {
    const int t = threadIdx.x;  // 256 threads, one partial each
    float mn = ws[896 + t];
    float sm = ws[1152 + t];
    __shared__ float smn[4], ssm[4];
    #pragma unroll
    for (int off = 32; off > 0; off >>= 1) {
        mn = fminf(mn, __shfl_down(mn, off, 64));
        sm += __shfl_down(sm, off, 64);
    }
    if ((t & 63) == 0) { smn[t >> 6] = mn; ssm[t >> 6] = sm; }
    __syncthreads();
    if (t == 0) {
        out[0] = fminf(fminf(smn[0], smn[1]), fminf(smn[2], smn[3]));
        out[1] = (ssm[0] + ssm[1] + ssm[2] + ssm[3]) * (1.0f / 32768.0f);
    }
}

extern "C" void kernel_launch(void* const* d_in, const int* in_sizes, int n_in,
                              void* d_out, int out_size, void* d_ws, size_t ws_size,
                              hipStream_t stream) {
    const float* x      = (const float*)d_in[0];
    const float* protos = (const float*)d_in[1];
    const float* w      = (const float*)d_in[2];
    const float* bias   = (const float*)d_in[3];
    float* out = (float*)d_out;
    float* ws  = (float*)d_ws;

    pc_stage1<<<NOUT + PBLK, 320, 0, stream>>>(protos, w, ws);
    pc_dist<<<DBLK, 128, 0, stream>>>(x, ws);
    pc_out<<<2048, 256, 0, stream>>>(bias, ws, out);
    pc_finish<<<1, 256, 0, stream>>>(ws, out);
}